// Round 6
// baseline (131.154 us; speedup 1.0000x reference)
//
#include <hip/hip_runtime.h>
#include <hip/hip_bf16.h>

// Causal attention, B=2 NH=16 T=2048 D=64, fp32 I/O.
// R6: one 1024-thr block per (heavy iq=15-p, light iq=p) q-tile pair.
// 4 groups x 4 waves split the pair's uniform 68 TK=32 k-tiles into 4x17
// supersteps -> 16 waves/CU with zero tail. Crossing group parks heavy
// partial in bf16 regs, switches to light. End: LDS add-round combine
// (l first, then O-heavy pass, then O-light pass). No global atomics.

typedef __bf16 bf16;
typedef __bf16 bf16x4 __attribute__((ext_vector_type(4)));
typedef __bf16 bf16x8 __attribute__((ext_vector_type(8)));
typedef float floatx4 __attribute__((ext_vector_type(4)));

#define T_SEQ 2048
#define DH 64
#define TQ 128
#define TKS 32
#define BHN 32
#define CEXP 0.18033688011112042f  // (1/sqrt(64)) * log2(e)

__device__ __forceinline__ void gload16(const bf16* g, bf16* l) {
    __builtin_amdgcn_global_load_lds(
        (const __attribute__((address_space(1))) void*)g,
        (__attribute__((address_space(3))) void*)l, 16, 0, 0);
}

// ---------------- fused prepass (unchanged from R5) ----------------
__global__ __launch_bounds__(256) void prep(const float* __restrict__ K,
                                            const float* __restrict__ V,
                                            bf16* __restrict__ Kb,
                                            bf16* __restrict__ Vt) {
    const int bid = (int)blockIdx.x;
    const int tid = (int)threadIdx.x;
    if (bid < 1024) {
        const size_t i = ((size_t)bid * 256 + tid) * 16;
        float4 a = *(const float4*)(K + i + 0);
        float4 b = *(const float4*)(K + i + 4);
        float4 c = *(const float4*)(K + i + 8);
        float4 d = *(const float4*)(K + i + 12);
        bf16x8 o0, o1;
        o0[0]=(bf16)a.x; o0[1]=(bf16)a.y; o0[2]=(bf16)a.z; o0[3]=(bf16)a.w;
        o0[4]=(bf16)b.x; o0[5]=(bf16)b.y; o0[6]=(bf16)b.z; o0[7]=(bf16)b.w;
        o1[0]=(bf16)c.x; o1[1]=(bf16)c.y; o1[2]=(bf16)c.z; o1[3]=(bf16)c.w;
        o1[4]=(bf16)d.x; o1[5]=(bf16)d.y; o1[6]=(bf16)d.z; o1[7]=(bf16)d.w;
        *(bf16x8*)(Kb + i + 0) = o0;
        *(bf16x8*)(Kb + i + 8) = o1;
        return;
    }
    __shared__ bf16 tile[64][72];
    const int vb = bid - 1024;
    const int bh = vb & (BHN - 1);
    const int t0 = (vb >> 5) * 64;
    {
        const int r = tid >> 2;
        const int c = (tid & 3) * 16;
        const float* s = V + ((size_t)bh * T_SEQ + t0 + r) * DH + c;
        float4 f0 = *(const float4*)(s + 0);
        float4 f1 = *(const float4*)(s + 4);
        float4 f2 = *(const float4*)(s + 8);
        float4 f3 = *(const float4*)(s + 12);
        bf16x8 p0, p1;
        p0[0]=(bf16)f0.x; p0[1]=(bf16)f0.y; p0[2]=(bf16)f0.z; p0[3]=(bf16)f0.w;
        p0[4]=(bf16)f1.x; p0[5]=(bf16)f1.y; p0[6]=(bf16)f1.z; p0[7]=(bf16)f1.w;
        p1[0]=(bf16)f2.x; p1[1]=(bf16)f2.y; p1[2]=(bf16)f2.z; p1[3]=(bf16)f2.w;
        p1[4]=(bf16)f3.x; p1[5]=(bf16)f3.y; p1[6]=(bf16)f3.z; p1[7]=(bf16)f3.w;
        *(bf16x8*)&tile[r][c + 0] = p0;
        *(bf16x8*)&tile[r][c + 8] = p1;
    }
    __syncthreads();
    {
        const int d   = tid >> 2;
        const int tch = (tid & 3) * 16;
        bf16x8 o0, o1;
        #pragma unroll
        for (int j = 0; j < 8; ++j) { o0[j] = tile[tch + j][d]; o1[j] = tile[tch + 8 + j][d]; }
        bf16* o = Vt + ((size_t)bh * DH + d) * T_SEQ + t0 + tch;
        *(bf16x8*)(o + 0) = o0;
        *(bf16x8*)(o + 8) = o1;
    }
}

// ---------------- main flash kernel ----------------
// LDS (bf16 elems): K[g]@g*2048 ([32key][64d], 128B rows, 8-chunk XOR swizzle),
// V[g]@8192+g*2048 ([32 dpair][64]: row=d>>1, halves (d&1)*32+k),
// P[w]@16384+w*1024 ([16 qpair][64]). Total 64 KB.
// Combine reuse: LB floats @0 ([2 tile][4 w4][2 nt][64 lane]), CB @+4KB (32 KB).
__global__ __launch_bounds__(1024, 4)
void fa_fwd(const float* __restrict__ Qg, const bf16* __restrict__ Kb,
            const bf16* __restrict__ Vt, float* __restrict__ Og)
{
    __shared__ __align__(16) bf16 smem[32768];

    const int bid = (int)blockIdx.x;
    const int bh  = bid & (BHN - 1);
    const int p   = bid >> 5;              // 0..7
    const int q0h = (15 - p) * TQ;
    const int q0l = p * TQ;
    const int A   = 64 - 4 * p;            // heavy k-tile count (TK=32)

    const int tid  = (int)threadIdx.x;
    const int wave = tid >> 6;             // 0..15
    const int w4   = wave & 3;             // q-column subtile
    const int g2   = wave >> 2;            // k-group 0..3
    const int lane = tid & 63;
    const int quad = lane >> 4;
    const int l16  = lane & 15;
    const int rl   = lane >> 3;
    const int ch   = lane & 7;

    bf16* Ksh = smem + g2 * 2048;
    bf16* Vsh = smem + 8192 + g2 * 2048;
    bf16* Pw  = smem + 16384 + wave * 1024;

    const bf16* Kbh = Kb + (size_t)bh * (T_SEQ * DH);
    const bf16* Vbh = Vt + (size_t)bh * (DH * T_SEQ);
    const size_t qrb = (size_t)bh * T_SEQ;

    const int t0 = g2 * 17;
    bool isLight = (t0 >= A);
    int qw = (isLight ? q0l : q0h) + w4 * 32;

    bf16x8 qb[2][2];
    auto loadQ = [&](int qbase) {
        #pragma unroll
        for (int nt = 0; nt < 2; ++nt) {
            const int qrow = qbase + w4 * 32 + nt * 16 + l16;
            #pragma unroll
            for (int kk = 0; kk < 2; ++kk) {
                const float* s = Qg + (qrb + qrow) * DH + kk * 32 + quad * 8;
                float4 f0 = *(const float4*)(s);
                float4 f1 = *(const float4*)(s + 4);
                bf16x8 t;
                t[0]=(bf16)f0.x; t[1]=(bf16)f0.y; t[2]=(bf16)f0.z; t[3]=(bf16)f0.w;
                t[4]=(bf16)f1.x; t[5]=(bf16)f1.y; t[6]=(bf16)f1.z; t[7]=(bf16)f1.w;
                qb[nt][kk] = t;
            }
        }
    };
    loadQ(isLight ? q0l : q0h);

    floatx4 oacc[4][2];
    #pragma unroll
    for (int mt = 0; mt < 4; ++mt)
        #pragma unroll
        for (int nt = 0; nt < 2; ++nt) oacc[mt][nt] = (floatx4){0.f,0.f,0.f,0.f};
    float lpart[2] = {0.f, 0.f};
    bf16x4 parked[8];
    #pragma unroll
    for (int f = 0; f < 8; ++f) parked[f] = (bf16x4){(bf16)0.f,(bf16)0.f,(bf16)0.f,(bf16)0.f};
    float lparkH[2] = {0.f, 0.f};

    // staging maps (per-lane constants)
    const int srow = w4 * 8 + rl;          // 0..31
    const int sgch = ch ^ (srow & 7);      // swizzled global chunk
    const int vd   = srow * 2 + (sgch >> 2);
    const int vkc  = sgch & 3;

    for (int s = 0; s < 17; ++s) {
        const int t = t0 + s;
        if (!isLight && t >= A) {          // park heavy, switch to light (group-uniform)
            #pragma unroll
            for (int f = 0; f < 8; ++f) {
                bf16x4 w;
                #pragma unroll
                for (int e = 0; e < 4; ++e) w[e] = (bf16)oacc[f >> 1][f & 1][e];
                parked[f] = w;
            }
            lparkH[0] = lpart[0]; lparkH[1] = lpart[1];
            lpart[0] = lpart[1] = 0.f;
            #pragma unroll
            for (int mt = 0; mt < 4; ++mt)
                #pragma unroll
                for (int nt = 0; nt < 2; ++nt) oacc[mt][nt] = (floatx4){0.f,0.f,0.f,0.f};
            isLight = true;
            qw = q0l + w4 * 32;
            loadQ(q0l);
        }
        const int kt = isLight ? (t - A) : t;
        const int k0 = kt * TKS;

        gload16(Kbh + (size_t)(k0 + srow) * DH + sgch * 8, &Ksh[w4 * 512]);
        gload16(Vbh + (size_t)vd * T_SEQ + k0 + vkc * 8, &Vsh[w4 * 512]);
        __syncthreads();

        // ---- S^T = K · Q^T ----
        floatx4 sa[2][2];
        #pragma unroll
        for (int mt = 0; mt < 2; ++mt)
            #pragma unroll
            for (int nt = 0; nt < 2; ++nt) sa[mt][nt] = (floatx4){0.f,0.f,0.f,0.f};
        #pragma unroll
        for (int kk = 0; kk < 2; ++kk) {
            #pragma unroll
            for (int mt = 0; mt < 2; ++mt) {
                const int R = mt * 16 + l16;
                bf16x8 kf = *(const bf16x8*)&Ksh[R * 64 + (((kk * 4 + quad) ^ (R & 7)) * 8)];
                sa[mt][0] = __builtin_amdgcn_mfma_f32_16x16x32_bf16(kf, qb[0][kk], sa[mt][0], 0, 0, 0);
                sa[mt][1] = __builtin_amdgcn_mfma_f32_16x16x32_bf16(kf, qb[1][kk], sa[mt][1], 0, 0, 0);
            }
        }
        if (k0 + TKS - 1 > qw) {
            #pragma unroll
            for (int mt = 0; mt < 2; ++mt)
                #pragma unroll
                for (int nt = 0; nt < 2; ++nt) {
                    const int qg = qw + nt * 16 + l16;
                    #pragma unroll
                    for (int r = 0; r < 4; ++r) {
                        const int keyg = k0 + mt * 16 + quad * 4 + r;
                        if (keyg > qg) sa[mt][nt][r] = -INFINITY;
                    }
                }
        }
        // ---- exp2 + P^T -> LDS (packed b64) ----
        #pragma unroll
        for (int mt = 0; mt < 2; ++mt)
            #pragma unroll
            for (int nt = 0; nt < 2; ++nt) {
                bf16x4 w;
                #pragma unroll
                for (int r = 0; r < 4; ++r) {
                    const float pv = __builtin_amdgcn_exp2f(CEXP * sa[mt][nt][r]);
                    lpart[nt] += pv;
                    w[r] = (bf16)pv;
                }
                const int prow = nt * 8 + (l16 >> 1);
                const int slot = ((l16 & 1) * 4 + mt * 2 + (quad >> 1)) ^ (prow & 7);
                *(bf16x4*)&Pw[prow * 64 + slot * 8 + (quad & 1) * 4] = w;
            }
        // ---- P^T B-fragments ----
        bf16x8 pf[2];
        #pragma unroll
        for (int nt = 0; nt < 2; ++nt) {
            const int prow = nt * 8 + (l16 >> 1);
            const int slot = ((l16 & 1) * 4 + quad) ^ (prow & 7);
            pf[nt] = *(const bf16x8*)&Pw[prow * 64 + slot * 8];
        }
        // ---- O^T += V^T · P^T ----
        #pragma unroll
        for (int mt = 0; mt < 4; ++mt) {
            const int vrow = mt * 8 + (l16 >> 1);
            const int slot = ((l16 & 1) * 4 + quad) ^ (vrow & 7);
            bf16x8 vf = *(const bf16x8*)&Vsh[vrow * 64 + slot * 8];
            oacc[mt][0] = __builtin_amdgcn_mfma_f32_16x16x32_bf16(vf, pf[0], oacc[mt][0], 0, 0, 0);
            oacc[mt][1] = __builtin_amdgcn_mfma_f32_16x16x32_bf16(vf, pf[1], oacc[mt][1], 0, 0, 0);
        }
        __syncthreads();
    }

    // ================= combine (all through LDS, add-rounds) =================
    float* LB = (float*)smem;            // [2][4][2][64]
    float* CB = (float*)smem + 1024;     // [4 w4][8 frag][64 lane][4] = 32 KB

    const float hLs[2] = { isLight ? lparkH[0] : lpart[0], isLight ? lparkH[1] : lpart[1] };
    const float lLs[2] = { isLight ? lpart[0] : 0.f,       isLight ? lpart[1] : 0.f };

    // pass 1: l (both tiles) + heavy O
    for (int r = 0; r < 4; ++r) {
        if (g2 == r) {
            #pragma unroll
            for (int nt = 0; nt < 2; ++nt) {
                const int ih = ((0 * 4 + w4) * 2 + nt) * 64 + lane;
                const int il = ((1 * 4 + w4) * 2 + nt) * 64 + lane;
                LB[ih] = (r == 0) ? hLs[nt] : (LB[ih] + hLs[nt]);
                LB[il] = (r == 0) ? lLs[nt] : (LB[il] + lLs[nt]);
            }
            float* base = CB + w4 * 2048;
            #pragma unroll
            for (int f = 0; f < 8; ++f) {
                floatx4* a = (floatx4*)&base[(f * 64 + lane) * 4];
                floatx4 v;
                if (isLight) {
                    v = (floatx4){(float)parked[f][0], (float)parked[f][1],
                                  (float)parked[f][2], (float)parked[f][3]};
                } else {
                    v = oacc[f >> 1][f & 1];
                }
                if (r) v += *a;
                *a = v;
            }
        }
        __syncthreads();
    }

    // g0 finalizes heavy
    if (g2 == 0) {
        float invl[2];
        #pragma unroll
        for (int nt = 0; nt < 2; ++nt) {
            float sl = 0.f;
            #pragma unroll
            for (int qd = 0; qd < 4; ++qd)
                sl += LB[((0 * 4 + w4) * 2 + nt) * 64 + qd * 16 + l16];
            invl[nt] = 1.0f / sl;
        }
        float* base = CB + w4 * 2048;
        #pragma unroll
        for (int f = 0; f < 8; ++f) {
            floatx4 v = *(const floatx4*)&base[(f * 64 + lane) * 4];
            const int nt = f & 1, mt = f >> 1;
            float4 o;
            o.x = v[0] * invl[nt]; o.y = v[1] * invl[nt];
            o.z = v[2] * invl[nt]; o.w = v[3] * invl[nt];
            *(float4*)&Og[(qrb + q0h + w4 * 32 + nt * 16 + l16) * DH + mt * 16 + quad * 4] = o;
        }
    }
    __syncthreads();

    // pass 2: light O (reuse CB)
    for (int r = 0; r < 4; ++r) {
        if (g2 == r) {
            float* base = CB + w4 * 2048;
            #pragma unroll
            for (int f = 0; f < 8; ++f) {
                floatx4* a = (floatx4*)&base[(f * 64 + lane) * 4];
                floatx4 v = isLight ? oacc[f >> 1][f & 1] : (floatx4){0.f,0.f,0.f,0.f};
                if (r) v += *a;
                *a = v;
            }
        }
        __syncthreads();
    }

    // g1 finalizes light
    if (g2 == 1) {
        float invl[2];
        #pragma unroll
        for (int nt = 0; nt < 2; ++nt) {
            float sl = 0.f;
            #pragma unroll
            for (int qd = 0; qd < 4; ++qd)
                sl += LB[((1 * 4 + w4) * 2 + nt) * 64 + qd * 16 + l16];
            invl[nt] = 1.0f / sl;
        }
        float* base = CB + w4 * 2048;
        #pragma unroll
        for (int f = 0; f < 8; ++f) {
            floatx4 v = *(const floatx4*)&base[(f * 64 + lane) * 4];
            const int nt = f & 1, mt = f >> 1;
            float4 o;
            o.x = v[0] * invl[nt]; o.y = v[1] * invl[nt];
            o.z = v[2] * invl[nt]; o.w = v[3] * invl[nt];
            *(float4*)&Og[(qrb + q0l + w4 * 32 + nt * 16 + l16) * DH + mt * 16 + quad * 4] = o;
        }
    }
}

extern "C" void kernel_launch(void* const* d_in, const int* in_sizes, int n_in,
                              void* d_out, int out_size, void* d_ws, size_t ws_size,
                              hipStream_t stream) {
    const float* Q = (const float*)d_in[0];
    const float* K = (const float*)d_in[1];
    const float* V = (const float*)d_in[2];
    float* O = (float*)d_out;
    (void)in_sizes; (void)n_in; (void)out_size; (void)ws_size;

    const size_t nelem = (size_t)BHN * T_SEQ * DH;   // 4,194,304
    bf16* Kbf = (bf16*)d_ws;            // 8 MiB
    bf16* Vtb = Kbf + nelem;            // 8 MiB

    prep<<<dim3(2048), dim3(256), 0, stream>>>(K, V, Kbf, Vtb);
    fa_fwd<<<dim3(256), dim3(1024), 0, stream>>>(Q, Kbf, Vtb, O);
}